// Round 5
// baseline (607.331 us; speedup 1.0000x reference)
//
#include <hip/hip_runtime.h>
#include <math.h>

#define NQ 12
#define LAYERS 8
#define BATCH 4096

// One wave (64 threads) per batch element. State: 4096 complex amps
// = 64 per lane, held in registers (compile-time indexed only -> SROA).
// Amplitude flat index i = (reg << 6) | lane.
//   wire w in 0..5  -> reg bit (5-w)   (in-register 2x2 gate)
//   wire w in 6..11 -> lane bit (11-w) (shfl_xor butterfly gate)
// MODE 0: d_out = float[B*4096], real parts only (harness casts complex64
//         -> float32; 62MB npz at the inputs' 92.7% ratio confirms 67MB raw).
// MODE 1: d_out = float2[B*4096], interleaved re/im (out_size = 2*B*4096).
template <int MODE>
__global__ __launch_bounds__(64, 2)
void qsim_kernel(const float* __restrict__ x,
                 const float* __restrict__ input_params,
                 const float* __restrict__ weights,
                 float* __restrict__ out, long long out_elems) {
  const int b = blockIdx.x;
  const int lane = threadIdx.x & 63;

  float sr[64], si[64];
#pragma unroll
  for (int r = 0; r < 64; ++r) { sr[r] = 0.f; si[r] = 0.f; }
  sr[0] = (lane == 0) ? 1.f : 0.f;

  // Lane permutation composing CNOTs (6,7)(7,8)(8,9)(9,10)(10,11):
  // new[l] = old[sigma(l)], sigma(l) = l ^ ((l>>1)&31).
  // CNOT(5,6) (control reg bit0, target lane bit5) merged in:
  // odd regs pull from sigma^32.
  const int sigmaE = lane ^ ((lane >> 1) & 31);
  const int sigmaO = sigmaE ^ 32;

  const float* xb = x + b * (NQ * LAYERS);

#pragma unroll 1
  for (int l = 0; l < LAYERS; ++l) {
    // --- fused gate per wire: lane w (w<12) computes U_w = Rot_w * RY_w ---
    // U = [[g, -conj(h)], [h, conj(g)]]
    float gr, gi, hr, hi;
    {
      const int wi = (lane < NQ) ? lane : (NQ - 1);
      const int idx = l * NQ + wi;
      const float a = input_params[idx] * xb[idx];
      float sa, ca; sincosf(0.5f * a, &sa, &ca);
      const float phi = weights[idx * 3 + 0];
      const float th  = weights[idx * 3 + 1];
      const float om  = weights[idx * 3 + 2];
      float st, ct;    sincosf(0.5f * th, &st, &ct);
      float spp, cpp_; sincosf(0.5f * (phi + om), &spp, &cpp_);
      float smm, cmm;  sincosf(0.5f * (phi - om), &smm, &cmm);
      // Rot = [[alpha, -conj(beta)],[beta, conj(alpha)]]
      const float ar = ct * cpp_, ai = -ct * spp;
      const float br = st * cmm,  bi = -st * smm;
      gr = ar * ca - br * sa;
      gi = ai * ca + bi * sa;
      hr = br * ca + ar * sa;
      hi = bi * ca - ai * sa;
    }

    // --- register-bit gates: wires 0..5 (all indices compile-time) ---
#pragma unroll
    for (int w = 0; w < 6; ++w) {
      const float Gr = __shfl(gr, w), Gi = __shfl(gi, w);
      const float Hr = __shfl(hr, w), Hi = __shfl(hi, w);
      const int m = 1 << (5 - w);
#pragma unroll
      for (int r0 = 0; r0 < 64; ++r0) {
        if (r0 & m) continue;          // compile-time skip
        const int r1 = r0 | m;
        const float s0r = sr[r0], s0i = si[r0];
        const float s1r = sr[r1], s1i = si[r1];
        // new0 = g*s0 - conj(h)*s1 ; new1 = h*s0 + conj(g)*s1
        sr[r0] = Gr * s0r - Gi * s0i - Hr * s1r - Hi * s1i;
        si[r0] = Gr * s0i + Gi * s0r + Hi * s1r - Hr * s1i;
        sr[r1] = Hr * s0r - Hi * s0i + Gr * s1r + Gi * s1i;
        si[r1] = Hr * s0i + Hi * s0r + Gr * s1i - Gi * s1r;
      }
    }

    // --- lane-bit gates: wires 6..11 (runtime w-loop bounds code size) ---
#pragma unroll 1
    for (int w = 6; w < 12; ++w) {
      const float Gr = __shfl(gr, w), Gi = __shfl(gi, w);
      const float Hr = __shfl(hr, w), Hi = __shfl(hi, w);
      const int lb = 11 - w;
      const int mask = 1 << lb;
      const int bset = (lane >> lb) & 1;
      // b==0: d=g, o=-conj(h) ; b==1: d=conj(g), o=h
      const float Dr  = Gr;
      const float Di  = bset ? -Gi : Gi;
      const float Or_ = bset ?  Hr : -Hr;
      const float Oi  = Hi;
#pragma unroll
      for (int r = 0; r < 64; ++r) {
        const float pr = __shfl_xor(sr[r], mask);
        const float pi = __shfl_xor(si[r], mask);
        const float mr = sr[r], mi = si[r];
        sr[r] = Dr * mr - Di * mi + Or_ * pr - Oi * pi;
        si[r] = Dr * mi + Di * mr + Or_ * pi + Oi * pr;
      }
    }

    // --- CNOT ring, order (0,1)(1,2)...(10,11)(11,0) ---
    // (0,1)..(4,5): sequential in-place compile-time swaps (free renaming).
#pragma unroll
    for (int w = 0; w < 5; ++w) {
      const int cm = 1 << (5 - w);       // control bit mask
      const int tm = cm >> 1;            // target bit mask
#pragma unroll
      for (int r = 0; r < 64; ++r) {
        if ((r & cm) && !(r & tm)) {
          const int p = r | tm;
          float t;
          t = sr[r]; sr[r] = sr[p]; sr[p] = t;
          t = si[r]; si[r] = si[p]; si[p] = t;
        }
      }
    }
    // (5,6) + (6,7)..(10,11): single shuffle pass; odd regs fold in ^32.
#pragma unroll
    for (int r = 0; r < 64; ++r) {
      const int src = (r & 1) ? sigmaO : sigmaE;
      sr[r] = __shfl(sr[r], src);
      si[r] = __shfl(si[r], src);
    }
    // (11,0): control = lane bit0, target = reg bit5 -> odd lanes swap r<->r+32
    {
      const bool odd = (lane & 1) != 0;
#pragma unroll
      for (int r = 0; r < 32; ++r) {
        const float a0 = sr[r], b0 = sr[r + 32];
        sr[r]      = odd ? b0 : a0;
        sr[r + 32] = odd ? a0 : b0;
        const float a1 = si[r], b1 = si[r + 32];
        si[r]      = odd ? b1 : a1;
        si[r + 32] = odd ? a1 : b1;
      }
    }
  }

  // Store, fully coalesced, bounds-guarded against out_elems (floats).
  if (MODE == 0) {
    const long long base = (long long)b << NQ;
#pragma unroll
    for (int r = 0; r < 64; ++r) {
      const long long idx = base + (r << 6) + lane;
      if (idx < out_elems) out[idx] = sr[r];
    }
  } else {
    float2* ob = (float2*)out;
    const long long base = (long long)b << NQ;
#pragma unroll
    for (int r = 0; r < 64; ++r) {
      const long long idx = base + (r << 6) + lane;
      if (2 * idx + 1 < out_elems) ob[idx] = make_float2(sr[r], si[r]);
    }
  }
}

extern "C" void kernel_launch(void* const* d_in, const int* in_sizes, int n_in,
                              void* d_out, int out_size, void* d_ws, size_t ws_size,
                              hipStream_t stream) {
  const float* x  = (const float*)d_in[0];
  const float* ip = (const float*)d_in[1];
  const float* w  = (const float*)d_in[2];
  float* out = (float*)d_out;
  (void)in_sizes; (void)n_in; (void)d_ws; (void)ws_size;
  const long long total = (long long)BATCH << NQ;   // 16,777,216 amplitudes
  if ((long long)out_size == 2 * total) {
    qsim_kernel<1><<<BATCH, 64, 0, stream>>>(x, ip, w, out, (long long)out_size);
  } else {
    qsim_kernel<0><<<BATCH, 64, 0, stream>>>(x, ip, w, out, (long long)out_size);
  }
}